// Round 3
// baseline (721.250 us; speedup 1.0000x reference)
//
#include <hip/hip_runtime.h>
#include <hip/hip_bf16.h>

#define N_ENTITY 64368
#define N_REL 40
#define DIM 128
#define N_BASES 8
#define N_EDGES 500000
#define BATCH 64
#define SEED_LEN 32
#define NROWS (BATCH * SEED_LEN)            // 2048
#define SCAN_NB ((N_ENTITY + 255) / 256)    // 252

// ===========================================================================
// Counting sort by dst: hist -> 3-phase exclusive scan -> scatter packed meta
// ===========================================================================
__global__ __launch_bounds__(256) void k_hist(
    const int* __restrict__ edst, int* __restrict__ hist)
{
    int e = blockIdx.x * 256 + threadIdx.x;
    if (e < N_EDGES) atomicAdd(&hist[edst[e]], 1);
}

__global__ __launch_bounds__(256) void k_scan1(
    const int* __restrict__ hist, int* __restrict__ ptr,
    int* __restrict__ partial)
{
    __shared__ int s[256];
    int tid = threadIdx.x;
    int gid = blockIdx.x * 256 + tid;
    int v = (gid < N_ENTITY) ? hist[gid] : 0;
    s[tid] = v;
    __syncthreads();
    for (int off = 1; off < 256; off <<= 1) {
        int t = (tid >= off) ? s[tid - off] : 0;
        __syncthreads();
        s[tid] += t;
        __syncthreads();
    }
    if (gid < N_ENTITY) ptr[gid] = s[tid] - v;      // exclusive within block
    if (tid == 255) partial[blockIdx.x] = s[255];   // block total
}

__global__ __launch_bounds__(256) void k_scan2(
    const int* __restrict__ partial, int* __restrict__ poff)
{
    __shared__ int s[256];
    int tid = threadIdx.x;
    int v = (tid < SCAN_NB) ? partial[tid] : 0;
    s[tid] = v;
    __syncthreads();
    for (int off = 1; off < 256; off <<= 1) {
        int t = (tid >= off) ? s[tid - off] : 0;
        __syncthreads();
        s[tid] += t;
        __syncthreads();
    }
    if (tid < SCAN_NB) poff[tid] = s[tid] - v;      // exclusive block offsets
}

__global__ __launch_bounds__(256) void k_scan3(
    int* __restrict__ ptr, const int* __restrict__ poff,
    int* __restrict__ ptr_work)
{
    int gid = blockIdx.x * 256 + threadIdx.x;
    if (gid < N_ENTITY) {
        int p = ptr[gid] + poff[blockIdx.x];
        ptr[gid] = p;
        ptr_work[gid] = p;
    }
}

__global__ __launch_bounds__(256) void k_scatter(
    const int* __restrict__ esrc, const int* __restrict__ edst,
    const int* __restrict__ etype, int* __restrict__ ptr_work,
    int* __restrict__ meta)
{
    int e = blockIdx.x * 256 + threadIdx.x;
    if (e < N_EDGES) {
        int d = edst[e];
        int pos = atomicAdd(&ptr_work[d], 1);
        meta[pos] = esrc[e] * 64 + etype[e];   // pack (src,type), type < 64
    }
}

// ===========================================================================
// Gather: one wave per dst node; HALF-WAVE per edge (float4/lane = 512B row).
// Main loop = 4 edges/iter = 16 global_load_dwordx4 (16 KB in flight/wave).
// Coeffs via 2x ds_read_b128. Cross-half shfl_xor reduction at the end.
// Fused finalize (mean + root + bias), zero atomics, one write per node.
// ===========================================================================
#define ACC8(C0, C1, V0, V1, V2, V3, V4, V5, V6, V7)                         \
    acc.x += C0.x*V0.x + C0.y*V1.x + C0.z*V2.x + C0.w*V3.x                   \
           + C1.x*V4.x + C1.y*V5.x + C1.z*V6.x + C1.w*V7.x;                  \
    acc.y += C0.x*V0.y + C0.y*V1.y + C0.z*V2.y + C0.w*V3.y                   \
           + C1.x*V4.y + C1.y*V5.y + C1.z*V6.y + C1.w*V7.y;                  \
    acc.z += C0.x*V0.z + C0.y*V1.z + C0.z*V2.z + C0.w*V3.z                   \
           + C1.x*V4.z + C1.y*V5.z + C1.z*V6.z + C1.w*V7.z;                  \
    acc.w += C0.x*V0.w + C0.y*V1.w + C0.z*V2.w + C0.w*V3.w                   \
           + C1.x*V4.w + C1.y*V5.w + C1.z*V6.w + C1.w*V7.w;

__global__ __launch_bounds__(256) void k_gather(
    const int* __restrict__ ptr, const int* __restrict__ hist,
    const int* __restrict__ meta, const float* __restrict__ basis,
    const float* __restrict__ att, const float* __restrict__ root,
    const float* __restrict__ bias, float* __restrict__ agg)
{
    __shared__ float att_s[N_REL * N_BASES];   // 1280 B, rows 32 B (16B-aligned)
    int tid = threadIdx.x;
    for (int i = tid; i < N_REL * N_BASES; i += 256) att_s[i] = att[i];
    __syncthreads();

    int wid  = (int)((blockIdx.x * 256 + tid) >> 6);
    int lane = tid & 63;
    if (wid >= N_ENTITY) return;

    int half = lane >> 5;          // which edge of a pair this half-wave owns
    int l32  = lane & 31;          // dim group: dims 4*l32 .. 4*l32+3

    int p   = ptr[wid];
    int cnt = hist[wid];
    const size_t bstride = (size_t)N_ENTITY * DIM;

    float4 acc = {0.f, 0.f, 0.f, 0.f};

    int j = 0;
    for (; j + 3 < cnt; j += 4) {              // 4 edges per iteration
        int mA0 = meta[p + j + 0];
        int mA1 = meta[p + j + 1];
        int mB0 = meta[p + j + 2];
        int mB1 = meta[p + j + 3];
        int mA = half ? mA1 : mA0;
        int mB = half ? mB1 : mB0;
        const float* bA = basis + (size_t)(mA >> 6) * DIM + l32 * 4;
        const float* bB = basis + (size_t)(mB >> 6) * DIM + l32 * 4;

        float4 a0 = *(const float4*)(bA + 0 * bstride);
        float4 a1 = *(const float4*)(bA + 1 * bstride);
        float4 a2 = *(const float4*)(bA + 2 * bstride);
        float4 a3 = *(const float4*)(bA + 3 * bstride);
        float4 a4 = *(const float4*)(bA + 4 * bstride);
        float4 a5 = *(const float4*)(bA + 5 * bstride);
        float4 a6 = *(const float4*)(bA + 6 * bstride);
        float4 a7 = *(const float4*)(bA + 7 * bstride);
        float4 b0 = *(const float4*)(bB + 0 * bstride);
        float4 b1 = *(const float4*)(bB + 1 * bstride);
        float4 b2 = *(const float4*)(bB + 2 * bstride);
        float4 b3 = *(const float4*)(bB + 3 * bstride);
        float4 b4 = *(const float4*)(bB + 4 * bstride);
        float4 b5 = *(const float4*)(bB + 5 * bstride);
        float4 b6 = *(const float4*)(bB + 6 * bstride);
        float4 b7 = *(const float4*)(bB + 7 * bstride);

        float4 cA0 = *(const float4*)(att_s + (mA & 63) * N_BASES);
        float4 cA1 = *(const float4*)(att_s + (mA & 63) * N_BASES + 4);
        float4 cB0 = *(const float4*)(att_s + (mB & 63) * N_BASES);
        float4 cB1 = *(const float4*)(att_s + (mB & 63) * N_BASES + 4);

        ACC8(cA0, cA1, a0, a1, a2, a3, a4, a5, a6, a7)
        ACC8(cB0, cB1, b0, b1, b2, b3, b4, b5, b6, b7)
    }
    for (; j < cnt; j += 2) {                  // pair tail, half1 maskable
        int m0 = meta[p + j];
        bool has1 = (j + 1 < cnt);
        int m1 = has1 ? meta[p + j + 1] : m0;
        int m = half ? m1 : m0;
        float sc = (half && !has1) ? 0.0f : 1.0f;
        const float* bA = basis + (size_t)(m >> 6) * DIM + l32 * 4;

        float4 a0 = *(const float4*)(bA + 0 * bstride);
        float4 a1 = *(const float4*)(bA + 1 * bstride);
        float4 a2 = *(const float4*)(bA + 2 * bstride);
        float4 a3 = *(const float4*)(bA + 3 * bstride);
        float4 a4 = *(const float4*)(bA + 4 * bstride);
        float4 a5 = *(const float4*)(bA + 5 * bstride);
        float4 a6 = *(const float4*)(bA + 6 * bstride);
        float4 a7 = *(const float4*)(bA + 7 * bstride);

        float4 c0 = *(const float4*)(att_s + (m & 63) * N_BASES);
        float4 c1 = *(const float4*)(att_s + (m & 63) * N_BASES + 4);
        c0.x *= sc; c0.y *= sc; c0.z *= sc; c0.w *= sc;
        c1.x *= sc; c1.y *= sc; c1.z *= sc; c1.w *= sc;

        ACC8(c0, c1, a0, a1, a2, a3, a4, a5, a6, a7)
    }

    // cross-half reduction: lane i and lane i^32 hold partials for same dims
    acc.x += __shfl_xor(acc.x, 32, 64);
    acc.y += __shfl_xor(acc.y, 32, 64);
    acc.z += __shfl_xor(acc.z, 32, 64);
    acc.w += __shfl_xor(acc.w, 32, 64);

    if (half == 0) {
        float inv = 1.0f / fmaxf((float)cnt, 1.0f);
        int o = wid * DIM + l32 * 4;
        float4 r  = *(const float4*)(root + o);
        float4 bb = *(const float4*)(bias + l32 * 4);
        float4 outv;
        outv.x = acc.x * inv + r.x + bb.x;
        outv.y = acc.y * inv + r.y + bb.y;
        outv.z = acc.z * inv + r.z + bb.z;
        outv.w = acc.w * inv + r.w + bb.w;
        *(float4*)(agg + o) = outv;
    }
}

// ===========================================================================
// Attention stage 1: T = tanh(H_flat @ A), H_flat rows via seed_ids gather.
// ===========================================================================
__global__ __launch_bounds__(256) void k_attn_gemm(
    const int* __restrict__ seed_ids, const float* __restrict__ nodes,
    const float* __restrict__ A, float* __restrict__ T)
{
    __shared__ float As[DIM * 132];       // [d][j], stride 132 (16B aligned)
    __shared__ float Hs[16 * DIM];        // 16 rows

    int tid = threadIdx.x;
    int r0  = blockIdx.x * 16;

    for (int i = tid; i < DIM * DIM; i += 256) {
        int row = i >> 7, col = i & 127;
        As[row * 132 + col] = A[i];
    }
    for (int i = tid; i < 16 * DIM; i += 256) {
        int rr = i >> 7, d = i & 127;
        int nid = seed_ids[r0 + rr];
        Hs[rr * DIM + d] = nodes[(size_t)nid * DIM + d];
    }
    __syncthreads();

    int jx = tid & 31;        // 32 groups x 4 cols
    int iy = tid >> 5;        // 8 groups x 2 rows
    float acc[2][4] = {{0,0,0,0},{0,0,0,0}};

    for (int d = 0; d < DIM; ++d) {
        float h0 = Hs[(iy * 2 + 0) * DIM + d];
        float h1 = Hs[(iy * 2 + 1) * DIM + d];
        const float4 a4 = *(const float4*)(As + d * 132 + jx * 4);
        acc[0][0] += h0 * a4.x; acc[0][1] += h0 * a4.y;
        acc[0][2] += h0 * a4.z; acc[0][3] += h0 * a4.w;
        acc[1][0] += h1 * a4.x; acc[1][1] += h1 * a4.y;
        acc[1][2] += h1 * a4.z; acc[1][3] += h1 * a4.w;
    }
    #pragma unroll
    for (int i = 0; i < 2; ++i) {
        int r = r0 + iy * 2 + i;
        #pragma unroll
        for (int k = 0; k < 4; ++k)
            T[(size_t)r * DIM + jx * 4 + k] = tanhf(acc[i][k]);
    }
}

// ===========================================================================
// Attention stage 2: e = T@b, per-batch softmax over 32, u = attn@H.
// ===========================================================================
__global__ __launch_bounds__(256) void k_attn_pool(
    const int* __restrict__ seed_ids, const float* __restrict__ nodes,
    const float* __restrict__ T, const float* __restrict__ Bv,
    float* __restrict__ u, float* __restrict__ uT)
{
    __shared__ float part[SEED_LEN][9];
    __shared__ float attw[SEED_LEN];

    int b = blockIdx.x, tid = threadIdx.x;
    int s = tid >> 3, g = tid & 7;

    float pe = 0.0f;
    for (int jj = g; jj < DIM; jj += 8)
        pe += T[(size_t)(b * SEED_LEN + s) * DIM + jj] * Bv[jj];
    part[s][g] = pe;
    __syncthreads();

    if (tid < SEED_LEN) {
        float e = 0.0f;
        for (int k = 0; k < 8; ++k) e += part[tid][k];
        attw[tid] = e;
    }
    __syncthreads();

    if (tid == 0) {
        float mx = -1e30f;
        for (int k = 0; k < SEED_LEN; ++k) mx = fmaxf(mx, attw[k]);
        float ssum = 0.0f;
        for (int k = 0; k < SEED_LEN; ++k) {
            float v = expf(attw[k] - mx);
            attw[k] = v; ssum += v;
        }
        float inv = 1.0f / ssum;
        for (int k = 0; k < SEED_LEN; ++k) attw[k] *= inv;
    }
    __syncthreads();

    if (tid < DIM) {
        float acc = 0.0f;
        for (int k = 0; k < SEED_LEN; ++k) {
            int nid = seed_ids[b * SEED_LEN + k];
            acc += attw[k] * nodes[(size_t)nid * DIM + tid];
        }
        u[b * DIM + tid]  = acc;
        uT[tid * BATCH + b] = acc;
    }
}

// ===========================================================================
// Scores: out[b][n] = u[b]·nodes[n] + out_bias[n].
// ===========================================================================
__global__ __launch_bounds__(256) void k_scores(
    const float* __restrict__ nodes, const float* __restrict__ uT,
    const float* __restrict__ out_bias, float* __restrict__ out)
{
    __shared__ float Nl[DIM * 65];   // [d][n], stride 65

    int tid = threadIdx.x;
    int n0  = blockIdx.x * 64;

    for (int i = tid; i < 64 * DIM; i += 256) {
        int n = i >> 7, d = i & 127;
        int gn = n0 + n;
        Nl[d * 65 + n] = (gn < N_ENTITY) ? nodes[(size_t)gn * DIM + d] : 0.0f;
    }
    __syncthreads();

    int w    = __builtin_amdgcn_readfirstlane(tid >> 6);
    int lane = tid & 63;
    int b0   = w * 16;

    float acc[16];
    #pragma unroll
    for (int k = 0; k < 16; ++k) acc[k] = 0.0f;

    #pragma unroll 4
    for (int d = 0; d < DIM; ++d) {
        float nv = Nl[d * 65 + lane];
        const float* up = uT + d * BATCH + b0;
        #pragma unroll
        for (int k = 0; k < 16; ++k) acc[k] += up[k] * nv;
    }

    int gn = n0 + lane;
    if (gn < N_ENTITY) {
        float ob = out_bias[gn];
        #pragma unroll
        for (int k = 0; k < 16; ++k)
            out[(size_t)(b0 + k) * N_ENTITY + gn] = acc[k] + ob;
    }
}

// ===========================================================================
extern "C" void kernel_launch(void* const* d_in, const int* in_sizes, int n_in,
                              void* d_out, int out_size, void* d_ws, size_t ws_size,
                              hipStream_t stream)
{
    const int*   seed_ids  = (const int*)d_in[0];
    const int*   esrc      = (const int*)d_in[1];
    const int*   edst      = (const int*)d_in[2];
    const int*   etype     = (const int*)d_in[3];
    const float* basis     = (const float*)d_in[4];
    const float* att       = (const float*)d_in[5];
    const float* root      = (const float*)d_in[6];
    const float* rgcn_bias = (const float*)d_in[7];
    const float* attn_a    = (const float*)d_in[8];
    const float* attn_b    = (const float*)d_in[9];
    const float* out_bias  = (const float*)d_in[10];
    float* out = (float*)d_out;

    float* agg      = (float*)d_ws;                          // 8,239,104
    int*   hist     = (int*)(agg + (size_t)N_ENTITY * DIM);  // 64,368
    int*   ptr      = hist + N_ENTITY;                       // 64,368
    int*   ptr_work = ptr + N_ENTITY;                        // 64,368
    int*   partial  = ptr_work + N_ENTITY;                   // 256
    int*   poff     = partial + 256;                         // 256
    int*   meta     = poff + 256;                            // 500,000
    float* T        = (float*)(meta + N_EDGES);              // 262,144
    float* u        = T + (size_t)NROWS * DIM;               // 8,192
    float* uT       = u + BATCH * DIM;                       // 8,192

    hipMemsetAsync(hist, 0, N_ENTITY * sizeof(int), stream);

    k_hist<<<(N_EDGES + 255) / 256, 256, 0, stream>>>(edst, hist);
    k_scan1<<<SCAN_NB, 256, 0, stream>>>(hist, ptr, partial);
    k_scan2<<<1, 256, 0, stream>>>(partial, poff);
    k_scan3<<<SCAN_NB, 256, 0, stream>>>(ptr, poff, ptr_work);
    k_scatter<<<(N_EDGES + 255) / 256, 256, 0, stream>>>(
        esrc, edst, etype, ptr_work, meta);

    k_gather<<<(N_ENTITY * 64 + 255) / 256, 256, 0, stream>>>(
        ptr, hist, meta, basis, att, root, rgcn_bias, agg);

    k_attn_gemm<<<NROWS / 16, 256, 0, stream>>>(seed_ids, agg, attn_a, T);
    k_attn_pool<<<BATCH, 256, 0, stream>>>(seed_ids, agg, T, attn_b, u, uT);

    k_scores<<<(N_ENTITY + 63) / 64, 256, 0, stream>>>(agg, uT, out_bias, out);
}

// Round 4
// 626.633 us; speedup vs baseline: 1.1510x; 1.1510x over previous
//
#include <hip/hip_runtime.h>
#include <hip/hip_bf16.h>

#define N_ENTITY 64368
#define N_REL 40
#define DIM 128
#define N_BASES 8
#define N_EDGES 500000
#define BATCH 64
#define SEED_LEN 32
#define NROWS (BATCH * SEED_LEN)            // 2048
#define SCAN_NB ((N_ENTITY + 255) / 256)    // 252
#define NPAD (SCAN_NB * 256)                // 64512 (block-aligned entity count)

// ===========================================================================
// Fused double counting-sort (by dst AND by src).
// hist2/ptr2/work2 are [2*NPAD]: dst half at offset 0, src half at NPAD.
// ===========================================================================
__global__ __launch_bounds__(256) void k_hist2(
    const int* __restrict__ edst, const int* __restrict__ esrc,
    int* __restrict__ hist2)
{
    int e = blockIdx.x * 256 + threadIdx.x;
    if (e < N_EDGES) {
        atomicAdd(&hist2[edst[e]], 1);
        atomicAdd(&hist2[NPAD + esrc[e]], 1);
    }
}

__global__ __launch_bounds__(256) void k_scan1(
    const int* __restrict__ hist2, int* __restrict__ ptr2,
    int* __restrict__ partial)                    // 2*SCAN_NB blocks
{
    __shared__ int s[256];
    int tid = threadIdx.x;
    int gid = blockIdx.x * 256 + tid;             // < 2*NPAD always
    int v = hist2[gid];
    s[tid] = v;
    __syncthreads();
    for (int off = 1; off < 256; off <<= 1) {
        int t = (tid >= off) ? s[tid - off] : 0;
        __syncthreads();
        s[tid] += t;
        __syncthreads();
    }
    ptr2[gid] = s[tid] - v;                       // exclusive within block
    if (tid == 255) partial[blockIdx.x] = s[255];
}

__global__ __launch_bounds__(256) void k_scan2(
    const int* __restrict__ partial, int* __restrict__ poff)   // 2 blocks
{
    __shared__ int s[256];
    int tid = threadIdx.x;
    int base = blockIdx.x * SCAN_NB;
    int v = (tid < SCAN_NB) ? partial[base + tid] : 0;
    s[tid] = v;
    __syncthreads();
    for (int off = 1; off < 256; off <<= 1) {
        int t = (tid >= off) ? s[tid - off] : 0;
        __syncthreads();
        s[tid] += t;
        __syncthreads();
    }
    if (tid < SCAN_NB) poff[base + tid] = s[tid] - v;
}

__global__ __launch_bounds__(256) void k_scan3(
    int* __restrict__ ptr2, const int* __restrict__ poff,
    int* __restrict__ work2)                      // 2*SCAN_NB blocks
{
    int gid = blockIdx.x * 256 + threadIdx.x;
    int p = ptr2[gid] + poff[blockIdx.x];
    ptr2[gid] = p;
    work2[gid] = p;
}

// Main-path scatter: computes this edge's dst-sorted position AND stores the
// src-sorted payload pack(dstpos, type) in one pass.
__global__ __launch_bounds__(256) void k_scatter2(
    const int* __restrict__ esrc, const int* __restrict__ edst,
    const int* __restrict__ etype, int* __restrict__ work2,
    int* __restrict__ payload)
{
    int e = blockIdx.x * 256 + threadIdx.x;
    if (e < N_EDGES) {
        int dpos = atomicAdd(&work2[edst[e]], 1);
        int spos = atomicAdd(&work2[NPAD + esrc[e]], 1);
        payload[spos] = dpos * 64 + etype[e];     // dpos<2^19, type<64
    }
}

// Fallback-path scatter (dst only): packed (src,type) meta, R2-style.
__global__ __launch_bounds__(256) void k_scatterD(
    const int* __restrict__ esrc, const int* __restrict__ edst,
    const int* __restrict__ etype, int* __restrict__ work2,
    int* __restrict__ meta)
{
    int e = blockIdx.x * 256 + threadIdx.x;
    if (e < N_EDGES) {
        int pos = atomicAdd(&work2[edst[e]], 1);
        meta[pos] = esrc[e] * 64 + etype[e];
    }
}

// ===========================================================================
// MAIN PATH Phase A: one HALF-WAVE per src node. Loads the 8 basis rows for
// this src once (consecutive srcs -> sequential 512B segments per plane =
// streaming), then for each outgoing edge computes m = sum_b c_b*row_b and
// writes it to the dst-sorted slot msg[dstpos] (scattered 512B writes).
// ===========================================================================
__global__ __launch_bounds__(256) void k_phaseA(
    const int* __restrict__ sptr, const int* __restrict__ shist,
    const int* __restrict__ payload, const float* __restrict__ basis,
    const float* __restrict__ att, float* __restrict__ msg)
{
    __shared__ float att_s[N_REL * N_BASES];
    int tid = threadIdx.x;
    for (int i = tid; i < N_REL * N_BASES; i += 256) att_s[i] = att[i];
    __syncthreads();

    int sid = (blockIdx.x * 256 + tid) >> 5;      // half-wave id == src id
    int l32 = tid & 31;
    if (sid >= N_ENTITY) return;
    int cnt = shist[sid];
    if (cnt == 0) return;
    int p = sptr[sid];

    const size_t bstride = (size_t)N_ENTITY * DIM;
    const float* bp = basis + (size_t)sid * DIM + l32 * 4;
    float4 r0 = *(const float4*)(bp + 0 * bstride);
    float4 r1 = *(const float4*)(bp + 1 * bstride);
    float4 r2 = *(const float4*)(bp + 2 * bstride);
    float4 r3 = *(const float4*)(bp + 3 * bstride);
    float4 r4 = *(const float4*)(bp + 4 * bstride);
    float4 r5 = *(const float4*)(bp + 5 * bstride);
    float4 r6 = *(const float4*)(bp + 6 * bstride);
    float4 r7 = *(const float4*)(bp + 7 * bstride);

    int j = 0;
    for (; j + 1 < cnt; j += 2) {                 // 2 edges in flight
        int plA = payload[p + j];
        int plB = payload[p + j + 1];
        const float* cA = att_s + (plA & 63) * N_BASES;
        const float* cB = att_s + (plB & 63) * N_BASES;
        float4 cA0 = *(const float4*)(cA);
        float4 cA1 = *(const float4*)(cA + 4);
        float4 cB0 = *(const float4*)(cB);
        float4 cB1 = *(const float4*)(cB + 4);

        float4 mA, mB;
        mA.x = cA0.x*r0.x + cA0.y*r1.x + cA0.z*r2.x + cA0.w*r3.x
             + cA1.x*r4.x + cA1.y*r5.x + cA1.z*r6.x + cA1.w*r7.x;
        mA.y = cA0.x*r0.y + cA0.y*r1.y + cA0.z*r2.y + cA0.w*r3.y
             + cA1.x*r4.y + cA1.y*r5.y + cA1.z*r6.y + cA1.w*r7.y;
        mA.z = cA0.x*r0.z + cA0.y*r1.z + cA0.z*r2.z + cA0.w*r3.z
             + cA1.x*r4.z + cA1.y*r5.z + cA1.z*r6.z + cA1.w*r7.z;
        mA.w = cA0.x*r0.w + cA0.y*r1.w + cA0.z*r2.w + cA0.w*r3.w
             + cA1.x*r4.w + cA1.y*r5.w + cA1.z*r6.w + cA1.w*r7.w;
        mB.x = cB0.x*r0.x + cB0.y*r1.x + cB0.z*r2.x + cB0.w*r3.x
             + cB1.x*r4.x + cB1.y*r5.x + cB1.z*r6.x + cB1.w*r7.x;
        mB.y = cB0.x*r0.y + cB0.y*r1.y + cB0.z*r2.y + cB0.w*r3.y
             + cB1.x*r4.y + cB1.y*r5.y + cB1.z*r6.y + cB1.w*r7.y;
        mB.z = cB0.x*r0.z + cB0.y*r1.z + cB0.z*r2.z + cB0.w*r3.z
             + cB1.x*r4.z + cB1.y*r5.z + cB1.z*r6.z + cB1.w*r7.z;
        mB.w = cB0.x*r0.w + cB0.y*r1.w + cB0.z*r2.w + cB0.w*r3.w
             + cB1.x*r4.w + cB1.y*r5.w + cB1.z*r6.w + cB1.w*r7.w;

        *(float4*)(msg + (size_t)(plA >> 6) * DIM + l32 * 4) = mA;
        *(float4*)(msg + (size_t)(plB >> 6) * DIM + l32 * 4) = mB;
    }
    if (j < cnt) {
        int plA = payload[p + j];
        const float* cA = att_s + (plA & 63) * N_BASES;
        float4 cA0 = *(const float4*)(cA);
        float4 cA1 = *(const float4*)(cA + 4);
        float4 mA;
        mA.x = cA0.x*r0.x + cA0.y*r1.x + cA0.z*r2.x + cA0.w*r3.x
             + cA1.x*r4.x + cA1.y*r5.x + cA1.z*r6.x + cA1.w*r7.x;
        mA.y = cA0.x*r0.y + cA0.y*r1.y + cA0.z*r2.y + cA0.w*r3.y
             + cA1.x*r4.y + cA1.y*r5.y + cA1.z*r6.y + cA1.w*r7.y;
        mA.z = cA0.x*r0.z + cA0.y*r1.z + cA0.z*r2.z + cA0.w*r3.z
             + cA1.x*r4.z + cA1.y*r5.z + cA1.z*r6.z + cA1.w*r7.z;
        mA.w = cA0.x*r0.w + cA0.y*r1.w + cA0.z*r2.w + cA0.w*r3.w
             + cA1.x*r4.w + cA1.y*r5.w + cA1.z*r6.w + cA1.w*r7.w;
        *(float4*)(msg + (size_t)(plA >> 6) * DIM + l32 * 4) = mA;
    }
}

// ===========================================================================
// MAIN PATH Phase B: one wave per dst node; streaming-reduce its contiguous
// msg range; fused mean + root + bias; one float2 write per lane.
// ===========================================================================
__global__ __launch_bounds__(256) void k_phaseB(
    const int* __restrict__ dptr, const int* __restrict__ dhist,
    const float* __restrict__ msg, const float* __restrict__ root,
    const float* __restrict__ bias, float* __restrict__ agg)
{
    int wid  = (int)((blockIdx.x * 256 + threadIdx.x) >> 6);
    int lane = threadIdx.x & 63;
    if (wid >= N_ENTITY) return;
    int cnt = dhist[wid];
    int p   = dptr[wid];
    const float* mp = msg + (size_t)p * DIM + lane * 2;

    float ax = 0.f, ay = 0.f;
    int j = 0;
    for (; j + 3 < cnt; j += 4) {                 // 4 rows in flight (2 KB/wave)
        float2 v0 = *(const float2*)(mp + (size_t)(j + 0) * DIM);
        float2 v1 = *(const float2*)(mp + (size_t)(j + 1) * DIM);
        float2 v2 = *(const float2*)(mp + (size_t)(j + 2) * DIM);
        float2 v3 = *(const float2*)(mp + (size_t)(j + 3) * DIM);
        ax += (v0.x + v1.x) + (v2.x + v3.x);
        ay += (v0.y + v1.y) + (v2.y + v3.y);
    }
    for (; j < cnt; ++j) {
        float2 v = *(const float2*)(mp + (size_t)j * DIM);
        ax += v.x; ay += v.y;
    }

    float inv = 1.0f / fmaxf((float)cnt, 1.0f);
    int o = wid * DIM + lane * 2;
    float2 r  = *(const float2*)(root + o);
    float2 bb = *(const float2*)(bias + lane * 2);
    float2 outv;
    outv.x = ax * inv + r.x + bb.x;
    outv.y = ay * inv + r.y + bb.y;
    *(float2*)(agg + o) = outv;
}

// ===========================================================================
// FALLBACK PATH gather (R2 version): one wave per dst, half-wave per edge,
// random basis reads. Used only if ws_size can't hold the msg buffer.
// ===========================================================================
#define ACC8(C0, C1, V0, V1, V2, V3, V4, V5, V6, V7)                         \
    acc.x += C0.x*V0.x + C0.y*V1.x + C0.z*V2.x + C0.w*V3.x                   \
           + C1.x*V4.x + C1.y*V5.x + C1.z*V6.x + C1.w*V7.x;                  \
    acc.y += C0.x*V0.y + C0.y*V1.y + C0.z*V2.y + C0.w*V3.y                   \
           + C1.x*V4.y + C1.y*V5.y + C1.z*V6.y + C1.w*V7.y;                  \
    acc.z += C0.x*V0.z + C0.y*V1.z + C0.z*V2.z + C0.w*V3.z                   \
           + C1.x*V4.z + C1.y*V5.z + C1.z*V6.z + C1.w*V7.z;                  \
    acc.w += C0.x*V0.w + C0.y*V1.w + C0.z*V2.w + C0.w*V3.w                   \
           + C1.x*V4.w + C1.y*V5.w + C1.z*V6.w + C1.w*V7.w;

__global__ __launch_bounds__(256) void k_gather(
    const int* __restrict__ ptr, const int* __restrict__ hist,
    const int* __restrict__ meta, const float* __restrict__ basis,
    const float* __restrict__ att, const float* __restrict__ root,
    const float* __restrict__ bias, float* __restrict__ agg)
{
    __shared__ float att_s[N_REL * N_BASES];
    int tid = threadIdx.x;
    for (int i = tid; i < N_REL * N_BASES; i += 256) att_s[i] = att[i];
    __syncthreads();

    int wid  = (int)((blockIdx.x * 256 + tid) >> 6);
    int lane = tid & 63;
    if (wid >= N_ENTITY) return;

    int half = lane >> 5;
    int l32  = lane & 31;
    int p   = ptr[wid];
    int cnt = hist[wid];
    const size_t bstride = (size_t)N_ENTITY * DIM;

    float4 acc = {0.f, 0.f, 0.f, 0.f};
    int j = 0;
    for (; j + 3 < cnt; j += 4) {
        int mA0 = meta[p + j + 0];
        int mA1 = meta[p + j + 1];
        int mB0 = meta[p + j + 2];
        int mB1 = meta[p + j + 3];
        int mA = half ? mA1 : mA0;
        int mB = half ? mB1 : mB0;
        const float* bA = basis + (size_t)(mA >> 6) * DIM + l32 * 4;
        const float* bB = basis + (size_t)(mB >> 6) * DIM + l32 * 4;
        float4 a0 = *(const float4*)(bA + 0 * bstride);
        float4 a1 = *(const float4*)(bA + 1 * bstride);
        float4 a2 = *(const float4*)(bA + 2 * bstride);
        float4 a3 = *(const float4*)(bA + 3 * bstride);
        float4 a4 = *(const float4*)(bA + 4 * bstride);
        float4 a5 = *(const float4*)(bA + 5 * bstride);
        float4 a6 = *(const float4*)(bA + 6 * bstride);
        float4 a7 = *(const float4*)(bA + 7 * bstride);
        float4 b0 = *(const float4*)(bB + 0 * bstride);
        float4 b1 = *(const float4*)(bB + 1 * bstride);
        float4 b2 = *(const float4*)(bB + 2 * bstride);
        float4 b3 = *(const float4*)(bB + 3 * bstride);
        float4 b4 = *(const float4*)(bB + 4 * bstride);
        float4 b5 = *(const float4*)(bB + 5 * bstride);
        float4 b6 = *(const float4*)(bB + 6 * bstride);
        float4 b7 = *(const float4*)(bB + 7 * bstride);
        float4 cA0 = *(const float4*)(att_s + (mA & 63) * N_BASES);
        float4 cA1 = *(const float4*)(att_s + (mA & 63) * N_BASES + 4);
        float4 cB0 = *(const float4*)(att_s + (mB & 63) * N_BASES);
        float4 cB1 = *(const float4*)(att_s + (mB & 63) * N_BASES + 4);
        ACC8(cA0, cA1, a0, a1, a2, a3, a4, a5, a6, a7)
        ACC8(cB0, cB1, b0, b1, b2, b3, b4, b5, b6, b7)
    }
    for (; j < cnt; j += 2) {
        int m0 = meta[p + j];
        bool has1 = (j + 1 < cnt);
        int m1 = has1 ? meta[p + j + 1] : m0;
        int m = half ? m1 : m0;
        float sc = (half && !has1) ? 0.0f : 1.0f;
        const float* bA = basis + (size_t)(m >> 6) * DIM + l32 * 4;
        float4 a0 = *(const float4*)(bA + 0 * bstride);
        float4 a1 = *(const float4*)(bA + 1 * bstride);
        float4 a2 = *(const float4*)(bA + 2 * bstride);
        float4 a3 = *(const float4*)(bA + 3 * bstride);
        float4 a4 = *(const float4*)(bA + 4 * bstride);
        float4 a5 = *(const float4*)(bA + 5 * bstride);
        float4 a6 = *(const float4*)(bA + 6 * bstride);
        float4 a7 = *(const float4*)(bA + 7 * bstride);
        float4 c0 = *(const float4*)(att_s + (m & 63) * N_BASES);
        float4 c1 = *(const float4*)(att_s + (m & 63) * N_BASES + 4);
        c0.x *= sc; c0.y *= sc; c0.z *= sc; c0.w *= sc;
        c1.x *= sc; c1.y *= sc; c1.z *= sc; c1.w *= sc;
        ACC8(c0, c1, a0, a1, a2, a3, a4, a5, a6, a7)
    }

    acc.x += __shfl_xor(acc.x, 32, 64);
    acc.y += __shfl_xor(acc.y, 32, 64);
    acc.z += __shfl_xor(acc.z, 32, 64);
    acc.w += __shfl_xor(acc.w, 32, 64);

    if (half == 0) {
        float inv = 1.0f / fmaxf((float)cnt, 1.0f);
        int o = wid * DIM + l32 * 4;
        float4 r  = *(const float4*)(root + o);
        float4 bb = *(const float4*)(bias + l32 * 4);
        float4 outv;
        outv.x = acc.x * inv + r.x + bb.x;
        outv.y = acc.y * inv + r.y + bb.y;
        outv.z = acc.z * inv + r.z + bb.z;
        outv.w = acc.w * inv + r.w + bb.w;
        *(float4*)(agg + o) = outv;
    }
}

// ===========================================================================
// Attention stage 1: T = tanh(H_flat @ A)
// ===========================================================================
__global__ __launch_bounds__(256) void k_attn_gemm(
    const int* __restrict__ seed_ids, const float* __restrict__ nodes,
    const float* __restrict__ A, float* __restrict__ T)
{
    __shared__ float As[DIM * 132];
    __shared__ float Hs[16 * DIM];

    int tid = threadIdx.x;
    int r0  = blockIdx.x * 16;

    for (int i = tid; i < DIM * DIM; i += 256) {
        int row = i >> 7, col = i & 127;
        As[row * 132 + col] = A[i];
    }
    for (int i = tid; i < 16 * DIM; i += 256) {
        int rr = i >> 7, d = i & 127;
        int nid = seed_ids[r0 + rr];
        Hs[rr * DIM + d] = nodes[(size_t)nid * DIM + d];
    }
    __syncthreads();

    int jx = tid & 31;
    int iy = tid >> 5;
    float acc[2][4] = {{0,0,0,0},{0,0,0,0}};

    for (int d = 0; d < DIM; ++d) {
        float h0 = Hs[(iy * 2 + 0) * DIM + d];
        float h1 = Hs[(iy * 2 + 1) * DIM + d];
        const float4 a4 = *(const float4*)(As + d * 132 + jx * 4);
        acc[0][0] += h0 * a4.x; acc[0][1] += h0 * a4.y;
        acc[0][2] += h0 * a4.z; acc[0][3] += h0 * a4.w;
        acc[1][0] += h1 * a4.x; acc[1][1] += h1 * a4.y;
        acc[1][2] += h1 * a4.z; acc[1][3] += h1 * a4.w;
    }
    #pragma unroll
    for (int i = 0; i < 2; ++i) {
        int r = r0 + iy * 2 + i;
        #pragma unroll
        for (int k = 0; k < 4; ++k)
            T[(size_t)r * DIM + jx * 4 + k] = tanhf(acc[i][k]);
    }
}

// ===========================================================================
// Attention stage 2: e = T@b, softmax over 32, u = attn@H (+ transpose)
// ===========================================================================
__global__ __launch_bounds__(256) void k_attn_pool(
    const int* __restrict__ seed_ids, const float* __restrict__ nodes,
    const float* __restrict__ T, const float* __restrict__ Bv,
    float* __restrict__ u, float* __restrict__ uT)
{
    __shared__ float part[SEED_LEN][9];
    __shared__ float attw[SEED_LEN];

    int b = blockIdx.x, tid = threadIdx.x;
    int s = tid >> 3, g = tid & 7;

    float pe = 0.0f;
    for (int jj = g; jj < DIM; jj += 8)
        pe += T[(size_t)(b * SEED_LEN + s) * DIM + jj] * Bv[jj];
    part[s][g] = pe;
    __syncthreads();

    if (tid < SEED_LEN) {
        float e = 0.0f;
        for (int k = 0; k < 8; ++k) e += part[tid][k];
        attw[tid] = e;
    }
    __syncthreads();

    if (tid == 0) {
        float mx = -1e30f;
        for (int k = 0; k < SEED_LEN; ++k) mx = fmaxf(mx, attw[k]);
        float ssum = 0.0f;
        for (int k = 0; k < SEED_LEN; ++k) {
            float v = expf(attw[k] - mx);
            attw[k] = v; ssum += v;
        }
        float inv = 1.0f / ssum;
        for (int k = 0; k < SEED_LEN; ++k) attw[k] *= inv;
    }
    __syncthreads();

    if (tid < DIM) {
        float acc = 0.0f;
        for (int k = 0; k < SEED_LEN; ++k) {
            int nid = seed_ids[b * SEED_LEN + k];
            acc += attw[k] * nodes[(size_t)nid * DIM + tid];
        }
        u[b * DIM + tid]  = acc;
        uT[tid * BATCH + b] = acc;
    }
}

// ===========================================================================
// Scores: out[b][n] = u[b]·nodes[n] + out_bias[n]
// ===========================================================================
__global__ __launch_bounds__(256) void k_scores(
    const float* __restrict__ nodes, const float* __restrict__ uT,
    const float* __restrict__ out_bias, float* __restrict__ out)
{
    __shared__ float Nl[DIM * 65];

    int tid = threadIdx.x;
    int n0  = blockIdx.x * 64;

    for (int i = tid; i < 64 * DIM; i += 256) {
        int n = i >> 7, d = i & 127;
        int gn = n0 + n;
        Nl[d * 65 + n] = (gn < N_ENTITY) ? nodes[(size_t)gn * DIM + d] : 0.0f;
    }
    __syncthreads();

    int w    = __builtin_amdgcn_readfirstlane(tid >> 6);
    int lane = tid & 63;
    int b0   = w * 16;

    float acc[16];
    #pragma unroll
    for (int k = 0; k < 16; ++k) acc[k] = 0.0f;

    #pragma unroll 4
    for (int d = 0; d < DIM; ++d) {
        float nv = Nl[d * 65 + lane];
        const float* up = uT + d * BATCH + b0;
        #pragma unroll
        for (int k = 0; k < 16; ++k) acc[k] += up[k] * nv;
    }

    int gn = n0 + lane;
    if (gn < N_ENTITY) {
        float ob = out_bias[gn];
        #pragma unroll
        for (int k = 0; k < 16; ++k)
            out[(size_t)(b0 + k) * N_ENTITY + gn] = acc[k] + ob;
    }
}

// ===========================================================================
extern "C" void kernel_launch(void* const* d_in, const int* in_sizes, int n_in,
                              void* d_out, int out_size, void* d_ws, size_t ws_size,
                              hipStream_t stream)
{
    const int*   seed_ids  = (const int*)d_in[0];
    const int*   esrc      = (const int*)d_in[1];
    const int*   edst      = (const int*)d_in[2];
    const int*   etype     = (const int*)d_in[3];
    const float* basis     = (const float*)d_in[4];
    const float* att       = (const float*)d_in[5];
    const float* root      = (const float*)d_in[6];
    const float* rgcn_bias = (const float*)d_in[7];
    const float* attn_a    = (const float*)d_in[8];
    const float* attn_b    = (const float*)d_in[9];
    const float* out_bias  = (const float*)d_in[10];
    float* out = (float*)d_out;

    const size_t AGG_F  = (size_t)N_ENTITY * DIM;        // 8,239,104
    const size_t MSG_F  = (size_t)N_EDGES * DIM;         // 64,000,000
    const size_t H2_I   = (size_t)2 * NPAD;              // 129,024

    // main-path workspace demand (in 4-byte words)
    const size_t main_words = AGG_F + MSG_F + 3 * H2_I + 1024
                            + N_EDGES + (size_t)NROWS * DIM + 2 * BATCH * DIM;
    bool big = ws_size >= main_words * 4;

    if (big) {
        float* agg     = (float*)d_ws;
        float* msg     = agg + AGG_F;
        int*   hist2   = (int*)(msg + MSG_F);
        int*   ptr2    = hist2 + H2_I;
        int*   work2   = ptr2 + H2_I;
        int*   part2   = work2 + H2_I;    // 512
        int*   poff2   = part2 + 512;     // 512
        int*   payload = poff2 + 512;
        float* T       = (float*)(payload + N_EDGES);
        float* u       = T + (size_t)NROWS * DIM;
        float* uT      = u + BATCH * DIM;

        hipMemsetAsync(hist2, 0, H2_I * sizeof(int), stream);
        k_hist2<<<(N_EDGES + 255) / 256, 256, 0, stream>>>(edst, esrc, hist2);
        k_scan1<<<2 * SCAN_NB, 256, 0, stream>>>(hist2, ptr2, part2);
        k_scan2<<<2, 256, 0, stream>>>(part2, poff2);
        k_scan3<<<2 * SCAN_NB, 256, 0, stream>>>(ptr2, poff2, work2);
        k_scatter2<<<(N_EDGES + 255) / 256, 256, 0, stream>>>(
            esrc, edst, etype, work2, payload);

        k_phaseA<<<N_ENTITY / 8, 256, 0, stream>>>(
            ptr2 + NPAD, hist2 + NPAD, payload, basis, att, msg);
        k_phaseB<<<N_ENTITY / 4, 256, 0, stream>>>(
            ptr2, hist2, msg, root, rgcn_bias, agg);

        k_attn_gemm<<<NROWS / 16, 256, 0, stream>>>(seed_ids, agg, attn_a, T);
        k_attn_pool<<<BATCH, 256, 0, stream>>>(seed_ids, agg, T, attn_b, u, uT);
        k_scores<<<(N_ENTITY + 63) / 64, 256, 0, stream>>>(agg, uT, out_bias, out);
    } else {
        // fallback: R2 dst-major gather (no msg buffer)
        float* agg     = (float*)d_ws;
        int*   hist2   = (int*)(agg + AGG_F);
        int*   ptr2    = hist2 + H2_I;
        int*   work2   = ptr2 + H2_I;
        int*   part2   = work2 + H2_I;
        int*   poff2   = part2 + 512;
        int*   meta    = poff2 + 512;
        float* T       = (float*)(meta + N_EDGES);
        float* u       = T + (size_t)NROWS * DIM;
        float* uT      = u + BATCH * DIM;

        hipMemsetAsync(hist2, 0, H2_I * sizeof(int), stream);
        k_hist2<<<(N_EDGES + 255) / 256, 256, 0, stream>>>(edst, esrc, hist2);
        k_scan1<<<2 * SCAN_NB, 256, 0, stream>>>(hist2, ptr2, part2);
        k_scan2<<<2, 256, 0, stream>>>(part2, poff2);
        k_scan3<<<2 * SCAN_NB, 256, 0, stream>>>(ptr2, poff2, work2);
        k_scatterD<<<(N_EDGES + 255) / 256, 256, 0, stream>>>(
            esrc, edst, etype, work2, meta);

        k_gather<<<(N_ENTITY * 64 + 255) / 256, 256, 0, stream>>>(
            ptr2, hist2, meta, basis, att, root, rgcn_bias, agg);

        k_attn_gemm<<<NROWS / 16, 256, 0, stream>>>(seed_ids, agg, attn_a, T);
        k_attn_pool<<<BATCH, 256, 0, stream>>>(seed_ids, agg, T, attn_b, u, uT);
        k_scores<<<(N_ENTITY + 63) / 64, 256, 0, stream>>>(agg, uT, out_bias, out);
    }
}